// Round 1
// baseline (518.769 us; speedup 1.0000x reference)
//
#include <hip/hip_runtime.h>
#include <hip/hip_bf16.h>
#include <cstddef>

// Problem: B=8, L=1024, E=1024, H=8, d=128
// out = BandedGaussianAttn(values @ Win^T) @ Wout^T
//
// Stage 1: V   = values @ Win^T        (sgemm_nt, M=8192,N=1024,K=1024)
// Stage 2: Att = gaussian stencil on V (17 taps, per-head offset)
// Stage 3: out = Att @ Wout^T          (sgemm_nt)

#define BATCH 8
#define SEQL  1024
#define EMB   1024
#define HEADS 8
#define HDIM  128

// -------- fp32 SGEMM: C[M,N] = A[M,K] * B[N,K]^T, all row-major --------
constexpr int BM = 128, BN = 128, BK = 16;

__global__ __launch_bounds__(256) void sgemm_nt(
    const float* __restrict__ A, const float* __restrict__ B,
    float* __restrict__ C, int M, int N, int K)
{
    __shared__ float As[BK][BM];
    __shared__ float Bs[BK][BN];
    const int tid = threadIdx.x;
    const int row0 = blockIdx.y * BM;
    const int col0 = blockIdx.x * BN;
    const int tx = tid & 15;      // 0..15
    const int ty = tid >> 4;      // 0..15
    const int lrow = tid >> 2;        // 0..63
    const int lc4  = (tid & 3) * 4;   // 0,4,8,12

    float acc[8][8];
    #pragma unroll
    for (int i = 0; i < 8; ++i)
        #pragma unroll
        for (int j = 0; j < 8; ++j) acc[i][j] = 0.f;

    for (int k0 = 0; k0 < K; k0 += BK) {
        #pragma unroll
        for (int half = 0; half < 2; ++half) {
            const int r = lrow + half * 64;
            const float4 av = *(const float4*)(A + (size_t)(row0 + r) * K + k0 + lc4);
            As[lc4 + 0][r] = av.x; As[lc4 + 1][r] = av.y;
            As[lc4 + 2][r] = av.z; As[lc4 + 3][r] = av.w;
            const float4 bv = *(const float4*)(B + (size_t)(col0 + r) * K + k0 + lc4);
            Bs[lc4 + 0][r] = bv.x; Bs[lc4 + 1][r] = bv.y;
            Bs[lc4 + 2][r] = bv.z; Bs[lc4 + 3][r] = bv.w;
        }
        __syncthreads();
        #pragma unroll
        for (int kk = 0; kk < BK; ++kk) {
            float a[8], b[8];
            *(float4*)&a[0] = *(const float4*)&As[kk][ty * 4];
            *(float4*)&a[4] = *(const float4*)&As[kk][64 + ty * 4];
            *(float4*)&b[0] = *(const float4*)&Bs[kk][tx * 4];
            *(float4*)&b[4] = *(const float4*)&Bs[kk][64 + tx * 4];
            #pragma unroll
            for (int i = 0; i < 8; ++i)
                #pragma unroll
                for (int j = 0; j < 8; ++j)
                    acc[i][j] += a[i] * b[j];
        }
        __syncthreads();
    }

    #pragma unroll
    for (int i = 0; i < 8; ++i) {
        const int r = row0 + ((i < 4) ? (ty * 4 + i) : (64 + ty * 4 + (i - 4)));
        float4 w0 = make_float4(acc[i][0], acc[i][1], acc[i][2], acc[i][3]);
        float4 w1 = make_float4(acc[i][4], acc[i][5], acc[i][6], acc[i][7]);
        *(float4*)(C + (size_t)r * N + col0 + tx * 4) = w0;
        *(float4*)(C + (size_t)r * N + col0 + 64 + tx * 4) = w1;
    }
}

// -------- banded gaussian attention stencil --------
// attended[b,q,e] = sum_{j=-R..R} w[j] * V[b, q + ofs[e/128] + j, e]
// w[j] = exp(-j^2/2)/sqrt(2*pi); taps beyond |j|=8 are < 6e-15 (negligible)
#define RAD 8

__constant__ float c_w[2 * RAD + 1] = {
    5.052271083536893e-15f, 9.134720408364594e-12f, 6.075882849823286e-09f,
    1.4867195147342979e-06f, 1.3383022576488537e-04f, 4.431848411938008e-03f,
    5.399096651318806e-02f,  2.4197072451914337e-01f, 3.989422804014327e-01f,
    2.4197072451914337e-01f, 5.399096651318806e-02f,  4.431848411938008e-03f,
    1.3383022576488537e-04f, 1.4867195147342979e-06f, 6.075882849823286e-09f,
    9.134720408364594e-12f,  5.052271083536893e-15f
};
__constant__ int c_ofs[HEADS] = { -3, -2, -1, 0, 0, 1, 2, 3 };

__global__ __launch_bounds__(256) void banded_attn(
    const float* __restrict__ V, const unsigned char* __restrict__ mask,
    float* __restrict__ Att)
{
    // one float4 per thread; e contiguous across threads -> coalesced
    const int idx = blockIdx.x * blockDim.x + threadIdx.x;   // over B*L*E/4
    const int e4n = EMB / 4;
    const int e  = (idx % e4n) * 4;
    const int rest = idx / e4n;
    const int q  = rest % SEQL;
    const int b  = rest / SEQL;
    const int h  = e >> 7;
    const int vbase = q + c_ofs[h];

    float4 acc = make_float4(0.f, 0.f, 0.f, 0.f);
    #pragma unroll
    for (int j = -RAD; j <= RAD; ++j) {
        const int vp = vbase + j;
        if (vp < 0 || vp >= SEQL) continue;
        if (mask[b * SEQL + vp]) continue;   // masked_fill on v rows
        const float w = c_w[j + RAD];
        const float4 val = *(const float4*)(V + ((size_t)(b * SEQL + vp)) * EMB + e);
        acc.x += w * val.x; acc.y += w * val.y;
        acc.z += w * val.z; acc.w += w * val.w;
    }
    *(float4*)(Att + ((size_t)(b * SEQL + q)) * EMB + e) = acc;
}

extern "C" void kernel_launch(void* const* d_in, const int* in_sizes, int n_in,
                              void* d_out, int out_size, void* d_ws, size_t ws_size,
                              hipStream_t stream) {
    const float* values = (const float*)d_in[0];
    // d_in[1] = queries: only its length matters (Lq == L), values unused
    const unsigned char* mask = (const unsigned char*)d_in[2];
    const float* Win  = (const float*)d_in[3];
    const float* Wout = (const float*)d_in[4];
    float* out = (float*)d_out;

    const int M = BATCH * SEQL;   // 8192
    const int N = EMB;            // 1024
    const int K = EMB;            // 1024

    float* V   = (float*)d_ws;                       // 32 MB
    float* Att = V + (size_t)M * EMB;                // 32 MB

    dim3 ggrid(N / BN, M / BM);   // (8, 64)
    sgemm_nt<<<ggrid, 256, 0, stream>>>(values, Win, V, M, N, K);

    const int total4 = (BATCH * SEQL * EMB) / 4;     // 2M float4
    banded_attn<<<total4 / 256, 256, 0, stream>>>(V, mask, Att);

    sgemm_nt<<<ggrid, 256, 0, stream>>>(Att, Wout, out, M, N, K);
}

// Round 2
// 105.519 us; speedup vs baseline: 4.9163x; 4.9163x over previous
//
#include <hip/hip_runtime.h>
#include <hip/hip_bf16.h>
#include <cstddef>

// Problem: B=8, L=1024, E=1024, H=8, d=128
// out = BandedGaussianAttn(values @ Win^T) @ Wout^T
// Pipeline (bf16 MFMA):
//   cvt:  values,Win,Wout fp32 -> bf16
//   GEMM1: Vb   = valb @ Winb^T   (bf16 in, bf16 out)   [MFMA 16x16x32]
//   stencil: Attb = 13-tap gaussian band over Vb (per-head offset), bf16->bf16
//   GEMM2: out  = Attb @ Woutb^T  (bf16 in, fp32 out)

#define BATCH 8
#define SEQL  1024
#define EMB   1024

typedef unsigned short u16;
typedef __attribute__((ext_vector_type(8))) short s16x8;
typedef __attribute__((ext_vector_type(4))) float f32x4;
typedef __attribute__((ext_vector_type(8))) unsigned short u16x8;

#define GLOAD_LDS16(g, l)                                                     \
    __builtin_amdgcn_global_load_lds(                                         \
        (const __attribute__((address_space(1))) void*)(g),                   \
        (__attribute__((address_space(3))) void*)(l), 16, 0, 0)

__device__ __forceinline__ u16 f2bf(float f) {
    unsigned u = __builtin_bit_cast(unsigned, f);
    u += 0x7FFF + ((u >> 16) & 1);        // round-to-nearest-even (finite inputs)
    return (u16)(u >> 16);
}
__device__ __forceinline__ float bf2f(u16 h) {
    return __builtin_bit_cast(float, (unsigned)h << 16);
}

// ---------------- fp32 -> bf16 convert, 8 elems/thread ----------------
__global__ __launch_bounds__(256) void cvt_f32_bf16(
    const float* __restrict__ in, u16* __restrict__ out)
{
    const int i = (blockIdx.x * 256 + threadIdx.x) * 8;
    float4 a = *(const float4*)(in + i);
    float4 b = *(const float4*)(in + i + 4);
    u16x8 o;
    o[0] = f2bf(a.x); o[1] = f2bf(a.y); o[2] = f2bf(a.z); o[3] = f2bf(a.w);
    o[4] = f2bf(b.x); o[5] = f2bf(b.y); o[6] = f2bf(b.z); o[7] = f2bf(b.w);
    *(u16x8*)(out + i) = o;
}

// ---------------- bf16 MFMA GEMM: C[M,N] = A[M,K] * B[N,K]^T ----------------
// m97-style: 128x128 tile, BK=32, 4 waves, 4x4 fragments of 16x16x32 per wave,
// global_load_lds width 16, single LDS buffer, 2 barriers per K-step.
template <bool OUT_BF16>
__global__ __launch_bounds__(256) void gemm_nt_bf16(
    const u16* __restrict__ A, const u16* __restrict__ B,
    void* __restrict__ Cout, int M, int N, int K)
{
    __shared__ u16 As[128 * 32];   // [row][k] row-major, 8 KB
    __shared__ u16 Bs[128 * 32];

    const int tid  = threadIdx.x;
    const int lane = tid & 63;
    const int wave = tid >> 6;
    const int row0 = blockIdx.y * 128;
    const int col0 = blockIdx.x * 128;

    // staging: thread t covers LDS elems [t*8, t*8+8) == row t>>2, kchunk t&3
    const int srow = tid >> 2;
    const int scol = (tid & 3) * 8;
    const size_t a_base = (size_t)(row0 + srow) * K + scol;
    const size_t b_base = (size_t)(col0 + srow) * K + scol;
    u16* As_w = &As[wave * 512];   // wave-uniform LDS base (lane lands +lane*16B)
    u16* Bs_w = &Bs[wave * 512];

    const int wr = (wave >> 1) * 64;   // wave's output sub-tile origin
    const int wc = (wave & 1) * 64;
    const int fr = lane & 15;
    const int fk = (lane >> 4) * 8;

    f32x4 acc[4][4] = {};

    for (int k0 = 0; k0 < K; k0 += 32) {
        GLOAD_LDS16(A + a_base + k0,                 As_w);
        GLOAD_LDS16(A + a_base + (size_t)64 * K + k0, As_w + 2048);
        GLOAD_LDS16(B + b_base + k0,                 Bs_w);
        GLOAD_LDS16(B + b_base + (size_t)64 * K + k0, Bs_w + 2048);
        __syncthreads();   // vmcnt(0) drain + barrier: tiles resident

        s16x8 af[4], bfr[4];
        #pragma unroll
        for (int m = 0; m < 4; ++m)
            af[m] = *(const s16x8*)&As[(wr + m * 16 + fr) * 32 + fk];
        #pragma unroll
        for (int n = 0; n < 4; ++n)
            bfr[n] = *(const s16x8*)&Bs[(wc + n * 16 + fr) * 32 + fk];
        #pragma unroll
        for (int m = 0; m < 4; ++m)
            #pragma unroll
            for (int n = 0; n < 4; ++n)
                acc[m][n] = __builtin_amdgcn_mfma_f32_16x16x32_bf16(
                    af[m], bfr[n], acc[m][n], 0, 0, 0);
        __syncthreads();   // protect LDS before next stage
    }

    // C/D layout (m89-verified): col = lane&15, row = (lane>>4)*4 + reg
    const int crow0 = row0 + wr + (lane >> 4) * 4;
    const int ccol0 = col0 + wc + fr;
    if (OUT_BF16) {
        u16* C = (u16*)Cout;
        #pragma unroll
        for (int m = 0; m < 4; ++m)
            #pragma unroll
            for (int n = 0; n < 4; ++n)
                #pragma unroll
                for (int j = 0; j < 4; ++j)
                    C[(size_t)(crow0 + m * 16 + j) * N + ccol0 + n * 16] =
                        f2bf(acc[m][n][j]);
    } else {
        float* C = (float*)Cout;
        #pragma unroll
        for (int m = 0; m < 4; ++m)
            #pragma unroll
            for (int n = 0; n < 4; ++n)
                #pragma unroll
                for (int j = 0; j < 4; ++j)
                    C[(size_t)(crow0 + m * 16 + j) * N + ccol0 + n * 16] =
                        acc[m][n][j];
    }
}

// ---------------- banded gaussian stencil (bf16 -> bf16) ----------------
// attended[b,q,e] = sum_{j=-R..R} pdf(j) * V[b, q + ofs[e/128] + j, e]
// pdf(7) = 9.1e-12 -> RAD=6 is exact to ~1e-8.
#define RAD 6
__constant__ float c_w[2 * RAD + 1] = {
    6.075882849823286e-09f, 1.4867195147342979e-06f, 1.3383022576488537e-04f,
    4.431848411938008e-03f, 5.399096651318806e-02f,  2.4197072451914337e-01f,
    3.989422804014327e-01f,
    2.4197072451914337e-01f, 5.399096651318806e-02f, 4.431848411938008e-03f,
    1.3383022576488537e-04f, 1.4867195147342979e-06f, 6.075882849823286e-09f
};
__constant__ int c_ofs[8] = { -3, -2, -1, 0, 0, 1, 2, 3 };

__global__ __launch_bounds__(256) void banded_attn(
    const u16* __restrict__ V, const unsigned char* __restrict__ mask,
    u16* __restrict__ Att)
{
    const int idx = blockIdx.x * 256 + threadIdx.x;  // over B*L*(E/8) = 1M
    const int e   = (idx & 127) * 8;                 // 8-elem chunk within E
    const int q   = (idx >> 7) & (SEQL - 1);
    const int b   = idx >> 17;
    const int h   = e >> 7;
    const int vbase = q + c_ofs[h];

    float acc[8] = {};
    #pragma unroll
    for (int j = -RAD; j <= RAD; ++j) {
        const int vp = vbase + j;
        if (vp < 0 || vp >= SEQL) continue;
        if (mask[b * SEQL + vp]) continue;           // masked_fill on v rows
        const float w = c_w[j + RAD];
        const u16x8 v = *(const u16x8*)&V[((size_t)(b * SEQL + vp)) * EMB + e];
        #pragma unroll
        for (int t = 0; t < 8; ++t) acc[t] = fmaf(w, bf2f(v[t]), acc[t]);
    }
    u16x8 o;
    #pragma unroll
    for (int t = 0; t < 8; ++t) o[t] = f2bf(acc[t]);
    *(u16x8*)&Att[((size_t)(b * SEQL + q)) * EMB + e] = o;
}

extern "C" void kernel_launch(void* const* d_in, const int* in_sizes, int n_in,
                              void* d_out, int out_size, void* d_ws, size_t ws_size,
                              hipStream_t stream) {
    const float* values = (const float*)d_in[0];
    // d_in[1] = queries: only its length matters (Lq == L)
    const unsigned char* mask = (const unsigned char*)d_in[2];
    const float* Win  = (const float*)d_in[3];
    const float* Wout = (const float*)d_in[4];
    float* out = (float*)d_out;

    const int M = BATCH * SEQL;   // 8192
    const int N = EMB;            // 1024
    const int K = EMB;            // 1024
    const size_t ME = (size_t)M * EMB;       // 8M elems
    const size_t WE = (size_t)EMB * EMB;     // 1M elems

    u16* valb  = (u16*)d_ws;          // 16 MB
    u16* Vb    = valb + ME;           // 16 MB
    u16* Attb  = Vb + ME;             // 16 MB
    u16* Winb  = Attb + ME;           // 2 MB
    u16* Woutb = Winb + WE;           // 2 MB   (total 52 MB)

    cvt_f32_bf16<<<(int)(ME / 8 / 256), 256, 0, stream>>>(values, valb);
    cvt_f32_bf16<<<(int)(WE / 8 / 256), 256, 0, stream>>>(Win, Winb);
    cvt_f32_bf16<<<(int)(WE / 8 / 256), 256, 0, stream>>>(Wout, Woutb);

    dim3 ggrid(N / 128, M / 128);   // (8, 64)
    gemm_nt_bf16<true><<<ggrid, 256, 0, stream>>>(valb, Winb, Vb, M, N, K);

    banded_attn<<<(int)(ME / 8 / 256), 256, 0, stream>>>(Vb, mask, Attb);

    gemm_nt_bf16<false><<<ggrid, 256, 0, stream>>>(Attb, Woutb, out, M, N, K);
}

// Round 3
// 83.394 us; speedup vs baseline: 6.2207x; 1.2653x over previous
//
#include <hip/hip_runtime.h>
#include <hip/hip_bf16.h>
#include <cstddef>

// B=8, L=1024, E=1024, H=8, d=128
// out = BandedGaussianAttn(values @ Win^T) @ Wout^T
// cvt(all) -> GEMM1(bf16->bf16) -> stencil(bf16) -> GEMM2(bf16->f32)
//
// GEMM: BM=256 BN=128 BK=64, 512thr/8waves(2Mx4N), per-wave 128x32,
// 3-buffer LDS pipeline, stage kt+2 / compute kt, vmcnt(6) counted waits,
// single raw s_barrier per K-tile, T2 XOR-chunk swizzle, T5 setprio, T1 XCD swizzle.

#define BATCH 8
#define SEQL  1024
#define EMB   1024

typedef unsigned short u16;
typedef __attribute__((ext_vector_type(8))) short s16x8;
typedef __attribute__((ext_vector_type(4))) float f32x4;
typedef __attribute__((ext_vector_type(8))) unsigned short u16x8;

#define GLOAD_LDS16(g, l)                                                     \
    __builtin_amdgcn_global_load_lds(                                         \
        (const __attribute__((address_space(1))) void*)(g),                   \
        (__attribute__((address_space(3))) void*)(l), 16, 0, 0)

__device__ __forceinline__ u16 f2bf(float f) {
    unsigned u = __builtin_bit_cast(unsigned, f);
    u += 0x7FFF + ((u >> 16) & 1);
    return (u16)(u >> 16);
}
__device__ __forceinline__ float bf2f(u16 h) {
    return __builtin_bit_cast(float, (unsigned)h << 16);
}

// ---------------- merged fp32 -> bf16 convert ----------------
// values: 1048576 chunks of 8; Win: 131072; Wout: 131072  => 5120 blocks
__global__ __launch_bounds__(256) void cvt_all(
    const float* __restrict__ v, const float* __restrict__ wi,
    const float* __restrict__ wo, u16* __restrict__ vb,
    u16* __restrict__ wib, u16* __restrict__ wob)
{
    const int i = blockIdx.x * 256 + threadIdx.x;
    const float* src; u16* dst; size_t off;
    if (i < 1048576)           { src = v;  dst = vb;  off = (size_t)i * 8; }
    else if (i < 1048576 + 131072) { src = wi; dst = wib; off = (size_t)(i - 1048576) * 8; }
    else                       { src = wo; dst = wob; off = (size_t)(i - 1179648) * 8; }
    float4 a = *(const float4*)(src + off);
    float4 b = *(const float4*)(src + off + 4);
    u16x8 o;
    o[0] = f2bf(a.x); o[1] = f2bf(a.y); o[2] = f2bf(a.z); o[3] = f2bf(a.w);
    o[4] = f2bf(b.x); o[5] = f2bf(b.y); o[6] = f2bf(b.z); o[7] = f2bf(b.w);
    *(u16x8*)(dst + off) = o;
}

// ---------------- pipelined bf16 MFMA GEMM: C[M,N] = A[M,K]*B[N,K]^T ----------------
constexpr int A_ELEMS = 256 * 64;          // 16384 elems, 32 KB
constexpr int B_ELEMS = 128 * 64;          // 8192 elems, 16 KB
constexpr int BUF_ELEMS = A_ELEMS + B_ELEMS;

template <bool OUT_BF16>
__global__ __launch_bounds__(512, 2) void gemm_nt_pipe(
    const u16* __restrict__ A, const u16* __restrict__ B,
    void* __restrict__ Cout, int M, int N, int K)
{
    __shared__ u16 lds[3 * BUF_ELEMS];     // 144 KB

    const int tid  = threadIdx.x;
    const int lane = tid & 63;
    const int wave = tid >> 6;

    // T1: bijective XCD swizzle (gridDim.x % 8 == 0)
    const int nwg = gridDim.x;
    const int bid = blockIdx.x;
    const int swz = (bid & 7) * (nwg >> 3) + (bid >> 3);
    const int ntile_n = N >> 7;                     // 8
    const int row0 = (swz / ntile_n) * 256;
    const int col0 = (swz % ntile_n) * 128;

    const int wm = wave >> 2;          // 0..1  (M half)
    const int wn = wave & 3;           // 0..3  (N quarter)
    const int fr = lane & 15;
    const int fg = lane >> 4;          // 0..3

    // staging coords: thread covers (row = c*64 + tid>>3, chunk = tid&7)
    const int srow   = tid >> 3;       // 0..63
    const int schunk = tid & 7;        // 16B chunk within 128B row

    f32x4 acc[8][2] = {};

    // stage K-tile kt into buffer b: LDS linear (row, chunk) holds
    // global (row, chunk ^ (row&7))  [T2 involution, rule 21]
    auto stage = [&](int b, int kt) {
        u16* Abuf = lds + b * BUF_ELEMS;
        u16* Bbuf = Abuf + A_ELEMS;
        const int k0 = kt << 6;
        #pragma unroll
        for (int c = 0; c < 4; ++c) {
            const int row = c * 64 + srow;
            const int sc  = ((schunk ^ (row & 7)) << 3);
            GLOAD_LDS16(A + (size_t)(row0 + row) * K + k0 + sc,
                        Abuf + c * 4096 + wave * 512);
        }
        #pragma unroll
        for (int c = 0; c < 2; ++c) {
            const int row = c * 64 + srow;
            const int sc  = ((schunk ^ (row & 7)) << 3);
            GLOAD_LDS16(B + (size_t)(col0 + row) * K + k0 + sc,
                        Bbuf + c * 4096 + wave * 512);
        }
    };

    auto compute = [&](int b) {
        const u16* Abuf = lds + b * BUF_ELEMS;
        const u16* Bbuf = Abuf + A_ELEMS;
        __builtin_amdgcn_s_setprio(1);
        #pragma unroll
        for (int kk = 0; kk < 2; ++kk) {
            s16x8 bf[2];
            #pragma unroll
            for (int n = 0; n < 2; ++n) {
                const int row = wn * 32 + n * 16 + fr;
                const int ch  = ((kk << 2) + fg) ^ (row & 7);
                bf[n] = *(const s16x8*)(Bbuf + row * 64 + ch * 8);
            }
            #pragma unroll
            for (int m = 0; m < 8; ++m) {
                const int row = wm * 128 + m * 16 + fr;
                const int ch  = ((kk << 2) + fg) ^ (row & 7);
                const s16x8 af = *(const s16x8*)(Abuf + row * 64 + ch * 8);
                acc[m][0] = __builtin_amdgcn_mfma_f32_16x16x32_bf16(af, bf[0], acc[m][0], 0, 0, 0);
                acc[m][1] = __builtin_amdgcn_mfma_f32_16x16x32_bf16(af, bf[1], acc[m][1], 0, 0, 0);
            }
        }
        __builtin_amdgcn_s_setprio(0);
    };

    const int NT = K >> 6;             // 16

    stage(0, 0);
    stage(1, 1);
    asm volatile("s_waitcnt vmcnt(6)" ::: "memory");   // tile 0 resident
    __builtin_amdgcn_s_barrier();
    asm volatile("" ::: "memory");

    for (int kt = 0; kt < NT - 2; ++kt) {
        stage((kt + 2) % 3, kt + 2);   // never the buffer being read
        compute(kt % 3);
        asm volatile("s_waitcnt vmcnt(6)" ::: "memory");  // tile kt+1 resident
        __builtin_amdgcn_s_barrier();
        asm volatile("" ::: "memory");
    }
    compute((NT - 2) % 3);
    asm volatile("s_waitcnt vmcnt(0)" ::: "memory");      // last tile resident
    __builtin_amdgcn_s_barrier();
    asm volatile("" ::: "memory");
    compute((NT - 1) % 3);

    // C/D layout: col = lane&15, row = fg*4 + j  (m89-verified convention)
    const int crow0 = row0 + wm * 128 + fg * 4;
    const int ccol0 = col0 + wn * 32 + fr;
    if (OUT_BF16) {
        u16* C = (u16*)Cout;
        #pragma unroll
        for (int m = 0; m < 8; ++m)
            #pragma unroll
            for (int n = 0; n < 2; ++n)
                #pragma unroll
                for (int j = 0; j < 4; ++j)
                    C[(size_t)(crow0 + m * 16 + j) * N + ccol0 + n * 16] =
                        f2bf(acc[m][n][j]);
    } else {
        float* C = (float*)Cout;
        #pragma unroll
        for (int m = 0; m < 8; ++m)
            #pragma unroll
            for (int n = 0; n < 2; ++n)
                #pragma unroll
                for (int j = 0; j < 4; ++j)
                    C[(size_t)(crow0 + m * 16 + j) * N + ccol0 + n * 16] =
                        acc[m][n][j];
    }
}

// ---------------- banded gaussian stencil (bf16 -> bf16) ----------------
#define RAD 6
__constant__ float c_w[2 * RAD + 1] = {
    6.075882849823286e-09f, 1.4867195147342979e-06f, 1.3383022576488537e-04f,
    4.431848411938008e-03f, 5.399096651318806e-02f,  2.4197072451914337e-01f,
    3.989422804014327e-01f,
    2.4197072451914337e-01f, 5.399096651318806e-02f, 4.431848411938008e-03f,
    1.3383022576488537e-04f, 1.4867195147342979e-06f, 6.075882849823286e-09f
};
__constant__ int c_ofs[8] = { -3, -2, -1, 0, 0, 1, 2, 3 };

__global__ __launch_bounds__(256) void banded_attn(
    const u16* __restrict__ V, const unsigned char* __restrict__ mask,
    u16* __restrict__ Att)
{
    const int idx = blockIdx.x * 256 + threadIdx.x;  // over B*L*(E/8) = 1M
    const int e   = (idx & 127) * 8;
    const int q   = (idx >> 7) & (SEQL - 1);
    const int b   = idx >> 17;
    const int h   = e >> 7;
    const int vbase = q + c_ofs[h];

    float acc[8] = {};
    #pragma unroll
    for (int j = -RAD; j <= RAD; ++j) {
        const int vp = vbase + j;
        if (vp < 0 || vp >= SEQL) continue;
        if (mask[b * SEQL + vp]) continue;
        const float w = c_w[j + RAD];
        const u16x8 v = *(const u16x8*)&V[((size_t)(b * SEQL + vp)) * EMB + e];
        #pragma unroll
        for (int t = 0; t < 8; ++t) acc[t] = fmaf(w, bf2f(v[t]), acc[t]);
    }
    u16x8 o;
    #pragma unroll
    for (int t = 0; t < 8; ++t) o[t] = f2bf(acc[t]);
    *(u16x8*)&Att[((size_t)(b * SEQL + q)) * EMB + e] = o;
}

extern "C" void kernel_launch(void* const* d_in, const int* in_sizes, int n_in,
                              void* d_out, int out_size, void* d_ws, size_t ws_size,
                              hipStream_t stream) {
    const float* values = (const float*)d_in[0];
    // d_in[1] = queries: only its length matters (Lq == L)
    const unsigned char* mask = (const unsigned char*)d_in[2];
    const float* Win  = (const float*)d_in[3];
    const float* Wout = (const float*)d_in[4];
    float* out = (float*)d_out;

    const int M = BATCH * SEQL;   // 8192
    const int N = EMB;            // 1024
    const int K = EMB;            // 1024
    const size_t ME = (size_t)M * EMB;     // 8M elems
    const size_t WE = (size_t)EMB * EMB;   // 1M elems

    u16* valb  = (u16*)d_ws;          // 16 MB
    u16* Vb    = valb + ME;           // 16 MB
    u16* Attb  = Vb + ME;             // 16 MB
    u16* Winb  = Attb + ME;           // 2 MB
    u16* Woutb = Winb + WE;           // 2 MB  (52 MB total)

    cvt_all<<<5120, 256, 0, stream>>>(values, Win, Wout, valb, Winb, Woutb);

    dim3 ggrid((M / 256) * (N / 128));   // 256 WGs
    gemm_nt_pipe<true><<<ggrid, 512, 0, stream>>>(valb, Winb, Vb, M, N, K);

    banded_attn<<<(int)(ME / 8 / 256), 256, 0, stream>>>(Vb, mask, Attb);

    gemm_nt_pipe<false><<<ggrid, 512, 0, stream>>>(Attb, Woutb, out, M, N, K);
}